// Round 7
// baseline (229.375 us; speedup 1.0000x reference)
//
#include <hip/hip_runtime.h>

typedef __bf16 bf16x8 __attribute__((ext_vector_type(8)));
typedef float floatx4 __attribute__((ext_vector_type(4)));
typedef float floatx16 __attribute__((ext_vector_type(16)));
typedef unsigned int u32;

#define BB 4
#define CC 256
#define NN 4096

__device__ __forceinline__ unsigned short f2bf(float f) {
  union { float f; unsigned u; } v; v.f = f;
  unsigned r = v.u + 0x7fffu + ((v.u >> 16) & 1u);
  return (unsigned short)(r >> 16);
}

__device__ __forceinline__ float bf2f(unsigned short s) {
  union { unsigned u; float f; } v; v.u = ((u32)s) << 16;
  return v.f;
}

__device__ __forceinline__ void async16(const void* g, void* l) {
  __builtin_amdgcn_global_load_lds((const __attribute__((address_space(1))) u32*)g,
                                   (__attribute__((address_space(3))) u32*)l, 16, 0, 0);
}

__device__ __forceinline__ u32 fbits(float f) {
  union { float f; u32 u; } v; v.f = f; return v.u;
}

// ---------------- GroupNorm stats: 128 blocks, each reduces a contiguous 32768-float group ----
__global__ __launch_bounds__(256) void gn_stats(const float* __restrict__ x, float* __restrict__ mr) {
  int bg = blockIdx.x;
  const float* p = x + (size_t)bg * 32768;
  int t = threadIdx.x;
  float s = 0.f, q = 0.f;
#pragma unroll
  for (int it = 0; it < 32; ++it) {
    float4 v = *(const float4*)(p + it * 1024 + t * 4);
    s += v.x + v.y + v.z + v.w;
    q += v.x * v.x + v.y * v.y + v.z * v.z + v.w * v.w;
  }
#pragma unroll
  for (int off = 1; off < 64; off <<= 1) {
    s += __shfl_xor(s, off, 64);
    q += __shfl_xor(q, off, 64);
  }
  __shared__ float red[8];
  int w = t >> 6;
  if ((t & 63) == 0) { red[w] = s; red[4 + w] = q; }
  __syncthreads();
  if (t == 0) {
    float S = red[0] + red[1] + red[2] + red[3];
    float Q = red[4] + red[5] + red[6] + red[7];
    float mean = S * (1.f / 32768.f);
    float var = Q * (1.f / 32768.f) - mean * mean;
    mr[bg] = mean;
    mr[128 + bg] = rsqrtf(var + 1e-5f);
  }
}

// ---------------- normalize + transpose to normed[b][n][c] bf16 ----------------
__global__ __launch_bounds__(256) void gn_apply(const float* __restrict__ x, const float* __restrict__ mr,
                                                const float* __restrict__ gamma, const float* __restrict__ beta,
                                                unsigned short* __restrict__ normed) {
  int bid = blockIdx.x;              // b * 4(ctile) * 64(ntile)
  int nt = bid & 63;
  int ct = (bid >> 6) & 3;
  int b = bid >> 8;
  int c0 = ct * 64, n0 = nt * 64;
  __shared__ unsigned short T[64][80];   // [n][c], padded
  int t = threadIdx.x;
#pragma unroll
  for (int it = 0; it < 4; ++it) {
    int idx = it * 256 + t;
    int cl = idx >> 4;
    int n4 = (idx & 15) * 4;
    int c = c0 + cl;
    int bg = b * 32 + (c >> 3);
    float mean = mr[bg], rstd = mr[128 + bg];
    float sc = rstd * gamma[c];
    float sh = beta[c] - mean * sc;
    float4 v = *(const float4*)(x + ((size_t)(b * CC + c)) * NN + n0 + n4);
    T[n4 + 0][cl] = f2bf(v.x * sc + sh);
    T[n4 + 1][cl] = f2bf(v.y * sc + sh);
    T[n4 + 2][cl] = f2bf(v.z * sc + sh);
    T[n4 + 3][cl] = f2bf(v.w * sc + sh);
  }
  __syncthreads();
#pragma unroll
  for (int it = 0; it < 2; ++it) {
    int idx = it * 256 + t;
    int nl = idx >> 3, ck = idx & 7;
    uint4 val;
    unsigned short* pv = (unsigned short*)&val;
#pragma unroll
    for (int j = 0; j < 8; ++j) pv[j] = T[nl][ck * 8 + j];
    *(uint4*)(normed + ((size_t)b * NN + n0 + nl) * CC + c0 + ck * 8) = val;
  }
}

// ---------------- weight fp32 -> bf16 (q rows pre-scaled by log2(e)/sqrt(C)) ----------------
__global__ __launch_bounds__(256) void wconv(const float* __restrict__ wqkv, const float* __restrict__ wproj,
                                             unsigned short* __restrict__ wq_bf, unsigned short* __restrict__ wp_bf) {
  int i = blockIdx.x * 256 + threadIdx.x;      // 1024 blocks -> 262144
  if (i < 196608) {
    float v = wqkv[i];
    if (i < 65536) v *= 0.090168440055560213f;  // log2(e)/16
    wq_bf[i] = f2bf(v);
  } else {
    int j = i - 196608;
    wp_bf[j] = f2bf(wproj[j]);
  }
}

// ---------------- B^T GEMM: C[M][Nc] = A[M][256] * B[Nc][256]^T  (128x128 tiles) ----------------
template <int RESID>
__global__ __launch_bounds__(256) void gemm_bt(const unsigned short* __restrict__ A,
                                               const unsigned short* __restrict__ Bm,
                                               void* __restrict__ Cout, const float* __restrict__ resid,
                                               int mtiles, int ldc,
                                               long sA, long sB, long sC, long sR) {
  int mt = blockIdx.x % mtiles;
  int nt = blockIdx.x / mtiles;
  int b = blockIdx.y;
  int m0 = mt * 128, n0 = nt * 128;
  __shared__ unsigned short As[128][72];
  __shared__ unsigned short Bs[128][72];
  int t = threadIdx.x;
  int w = t >> 6, lane = t & 63;
  int l16 = lane & 15, quad = lane >> 4;
  int wr = w >> 1, wc = w & 1;
  const unsigned short* Ab = A + (size_t)b * sA + (size_t)m0 * 256;
  const unsigned short* Bb = Bm + (size_t)b * sB + (size_t)n0 * 256;
  floatx4 acc[4][4];
#pragma unroll
  for (int m = 0; m < 4; ++m)
#pragma unroll
    for (int n = 0; n < 4; ++n)
#pragma unroll
      for (int r = 0; r < 4; ++r) acc[m][n][r] = 0.f;

  for (int kb = 0; kb < 4; ++kb) {
    __syncthreads();
#pragma unroll
    for (int i = 0; i < 4; ++i) {
      int idx = i * 256 + t;
      int r = idx >> 3, ck = idx & 7;
      *(uint4*)&As[r][ck * 8] = *(const uint4*)(Ab + (size_t)r * 256 + kb * 64 + ck * 8);
      *(uint4*)&Bs[r][ck * 8] = *(const uint4*)(Bb + (size_t)r * 256 + kb * 64 + ck * 8);
    }
    __syncthreads();
#pragma unroll
    for (int kk = 0; kk < 2; ++kk) {
      bf16x8 af[4], bfr[4];
#pragma unroll
      for (int m = 0; m < 4; ++m) af[m] = *(const bf16x8*)&As[wr * 64 + m * 16 + l16][kk * 32 + quad * 8];
#pragma unroll
      for (int n = 0; n < 4; ++n) bfr[n] = *(const bf16x8*)&Bs[wc * 64 + n * 16 + l16][kk * 32 + quad * 8];
#pragma unroll
      for (int m = 0; m < 4; ++m)
#pragma unroll
        for (int n = 0; n < 4; ++n)
          acc[m][n] = __builtin_amdgcn_mfma_f32_16x16x32_bf16(af[m], bfr[n], acc[m][n], 0, 0, 0);
    }
  }
  size_t cb = (size_t)b * sC;
  size_t rb = (size_t)b * sR;
#pragma unroll
  for (int m = 0; m < 4; ++m)
#pragma unroll
    for (int n = 0; n < 4; ++n)
#pragma unroll
      for (int r = 0; r < 4; ++r) {
        int row = m0 + wr * 64 + m * 16 + quad * 4 + r;
        int col = n0 + wc * 64 + n * 16 + l16;
        size_t idx = (size_t)row * ldc + col;
        if (RESID)
          ((float*)Cout)[cb + idx] = acc[m][n][r] + resid[rb + idx];
        else
          ((unsigned short*)Cout)[cb + idx] = f2bf(acc[m][n][r]);
      }
}

// ---------------- fused attention v7: 64-row register blocking, 4 waves, 1 wave/SIMD ---------
// grid 256 = 1 block/CU, 256 thr, 4 waves = 1/SIMD (cap 512 regs/wave). Block = (b, qt, kh):
// Q rows [qt*128,+128), K/V rows [kh*2048,+2048). Wave (ih, ch) owns O[ih*64..+64][ch*128..+128],
// full j; qreg[2][16] = 128 VGPR, oacc[2][4] = 128 AGPR. Each K/V fragment read from LDS feeds
// TWO MFMAs (both i-blocks) -> per-CU LDS traffic 192 KB read + 64 KB DMA write per iter
// (v6 was 384+64: the LDS pipe (~85-128 B/cyc/CU) was the binding resource).
// DMA double-buffer unchanged from v6 (layouts/swizzles identical, verified).
__global__ __launch_bounds__(256, 1) void attn(const unsigned short* __restrict__ qk,   // [B][N][512] (q|k)
                                               const unsigned short* __restrict__ vbuf, // [B][C][N]
                                               unsigned short* __restrict__ opart0,     // [B][N][C] bf16 (kh=0)
                                               unsigned short* __restrict__ opart1,     // [B][N][C] bf16 (kh=1)
                                               float* __restrict__ lpart) {             // [B*2][N]
  __shared__ __attribute__((aligned(16))) char smem[131072]; // K0|K1|V0|V1, 32 KB each

  int xcd = blockIdx.x & 7, slot = blockIdx.x >> 3;
  int b = xcd >> 1;
  int kh = xcd & 1;
  int i0 = slot * 128;
  int k0 = kh * 32;

  int t = threadIdx.x, w = t >> 6, l = t & 63;
  int l31 = l & 31, hi = l >> 5;
  int ih = w & 1;            // i-half (64 rows)
  int ch = w >> 1;           // c-half (128 cols)

  const size_t bqk = (size_t)b * NN * 512;
  const size_t bv = (size_t)b * CC * NN;

  // DMA stage of one K/V tile into buffer `buf` (v6 layouts: K [64 j][256 c] 16B-chunk XOR
  // swizzle p^(r&31); V [256 c][64 j] chunk swizzle p^(c&7); both DMA-compatible).
  auto stage = [&](int tile, int buf) {
    const unsigned short* kg = qk + bqk + (size_t)tile * 64 * 512 + 256;
    char* kb = smem + buf * 32768;
#pragma unroll
    for (int it = 0; it < 8; ++it) {
      int pp = w * 8 + it;                    // instr-block 0..31 (2 rows each)
      int r = 2 * pp + (l >> 5);
      int c = (l & 31) ^ (r & 31);
      async16(kg + (size_t)r * 512 + c * 8, kb + pp * 1024);
    }
    const unsigned short* vg = vbuf + bv + (size_t)tile * 64;
    char* vb = smem + 65536 + buf * 32768;
    int cj = (l & 7) ^ ((l >> 3) & 7);
#pragma unroll
    for (int it = 0; it < 8; ++it) {
      int pp = w * 8 + it;                    // instr-block 0..31 (8 c-rows each)
      int rc = 8 * pp + (l >> 3);
      async16(vg + (size_t)rc * NN + cj * 8, vb + pp * 1024);
    }
  };

  stage(k0, 0);

  // Q fragments (B-operand): qreg[ib]: lane = i = i0 + ih*64 + ib*32 + l31, elems c = ks*16+hi*8
  bf16x8 qreg[2][16];
#pragma unroll
  for (int ib = 0; ib < 2; ++ib) {
    const unsigned short* qp = qk + bqk + (size_t)(i0 + ih * 64 + ib * 32 + l31) * 512 + hi * 8;
#pragma unroll
    for (int ks = 0; ks < 16; ++ks)
      qreg[ib][ks] = *(const bf16x8*)(qp + ks * 16);
  }

  floatx16 oacc[2][4];
#pragma unroll
  for (int ib = 0; ib < 2; ++ib)
#pragma unroll
    for (int cf = 0; cf < 4; ++cf)
#pragma unroll
      for (int r = 0; r < 16; ++r) oacc[ib][cf][r] = 0.f;
  float lacc0 = 0.f, lacc1 = 0.f;

  for (int kt = 0; kt < 32; ++kt) {
    int cur = kt & 1;
    __syncthreads();                      // tile kt DMA drained; all waves past prev buf reads
    if (kt < 31) stage(k0 + kt + 1, cur ^ 1);   // in flight during compute below

    const unsigned short* Kc = (const unsigned short*)(smem + cur * 32768);
    const unsigned short* Vc = (const unsigned short*)(smem + 65536 + cur * 32768);

#pragma unroll
    for (int jh = 0; jh < 2; ++jh) {
      // S^T = K . Q^T for both i-blocks; each K fragment feeds 2 MFMAs
      floatx16 st0, st1;
#pragma unroll
      for (int r = 0; r < 16; ++r) { st0[r] = 0.f; st1[r] = 0.f; }
#pragma unroll
      for (int ks = 0; ks < 16; ++ks) {
        bf16x8 kf = *(const bf16x8*)&Kc[(jh * 32 + l31) * 256 + (((ks << 1) | hi) ^ l31) * 8];
        st0 = __builtin_amdgcn_mfma_f32_32x32x16_bf16(kf, qreg[0][ks], st0, 0, 0, 0);
        st1 = __builtin_amdgcn_mfma_f32_32x32x16_bf16(kf, qreg[1][ks], st1, 0, 0, 0);
      }
      // P = exp2(S^T); pack bf16 pairs along j (v_perm truncation; l stays fp32-accurate)
      u32 pr0[8], pr1[8];
#pragma unroll
      for (int k2 = 0; k2 < 8; ++k2) {
        float a0 = __builtin_amdgcn_exp2f(st0[2 * k2]);
        float a1 = __builtin_amdgcn_exp2f(st0[2 * k2 + 1]);
        lacc0 += a0 + a1;
        pr0[k2] = __builtin_amdgcn_perm(fbits(a1), fbits(a0), 0x07060302u);
        float b0 = __builtin_amdgcn_exp2f(st1[2 * k2]);
        float b1 = __builtin_amdgcn_exp2f(st1[2 * k2 + 1]);
        lacc1 += b0 + b1;
        pr1[k2] = __builtin_amdgcn_perm(fbits(b1), fbits(b0), 0x07060302u);
      }
      // rearrange into PV A-fragments (elems j = jh*32 + s*16 + hi*8 + 0..7) via hi-half exchange
      union U { u32 u[4]; bf16x8 v; } a0[2], a1[2];
#pragma unroll
      for (int ib = 0; ib < 2; ++ib) {
        u32* pr = ib ? pr1 : pr0;
        u32 sA = hi ? pr[0] : pr[2], sB = hi ? pr[1] : pr[3];
        u32 rA = (u32)__shfl_xor((int)sA, 32, 64);
        u32 rB = (u32)__shfl_xor((int)sB, 32, 64);
        a0[ib].u[0] = hi ? rA : pr[0]; a0[ib].u[1] = hi ? rB : pr[1];
        a0[ib].u[2] = hi ? pr[2] : rA; a0[ib].u[3] = hi ? pr[3] : rB;
        sA = hi ? pr[4] : pr[6]; sB = hi ? pr[5] : pr[7];
        rA = (u32)__shfl_xor((int)sA, 32, 64);
        rB = (u32)__shfl_xor((int)sB, 32, 64);
        a1[ib].u[0] = hi ? rA : pr[4]; a1[ib].u[1] = hi ? rB : pr[5];
        a1[ib].u[2] = hi ? pr[6] : rA; a1[ib].u[3] = hi ? pr[7] : rB;
      }
      // O += P . V ; each V fragment feeds 2 MFMAs (both i-blocks)
#pragma unroll
      for (int cf = 0; cf < 4; ++cf) {
        int c = ch * 128 + cf * 32 + l31;
        const unsigned short* vrow = Vc + c * 64;
        bf16x8 v0 = *(const bf16x8*)(vrow + (((jh * 4) | hi) ^ (l31 & 7)) * 8);
        oacc[0][cf] = __builtin_amdgcn_mfma_f32_32x32x16_bf16(a0[0].v, v0, oacc[0][cf], 0, 0, 0);
        oacc[1][cf] = __builtin_amdgcn_mfma_f32_32x32x16_bf16(a0[1].v, v0, oacc[1][cf], 0, 0, 0);
        bf16x8 v1 = *(const bf16x8*)(vrow + (((jh * 4 + 2) | hi) ^ (l31 & 7)) * 8);
        oacc[0][cf] = __builtin_amdgcn_mfma_f32_32x32x16_bf16(a1[0].v, v1, oacc[0][cf], 0, 0, 0);
        oacc[1][cf] = __builtin_amdgcn_mfma_f32_32x32x16_bf16(a1[1].v, v1, oacc[1][cf], 0, 0, 0);
      }
    }
  }

  // ---- epilogue: per-wave-owned O tiles -> direct bf16 stores; l complete after one shfl ----
  float l20 = lacc0 + __shfl_xor(lacc0, 32, 64);
  float l21 = lacc1 + __shfl_xor(lacc1, 32, 64);
  size_t pbl = (size_t)(b * 2 + kh) * NN + i0;
  if (ch == 0 && hi == 0) {
    lpart[pbl + ih * 64 + l31] = l20;
    lpart[pbl + ih * 64 + 32 + l31] = l21;
  }

  unsigned short* ops = kh ? opart1 : opart0;
  size_t rowbase = (size_t)b * NN + i0 + ih * 64;
#pragma unroll
  for (int ib = 0; ib < 2; ++ib)
#pragma unroll
    for (int cf = 0; cf < 4; ++cf)
#pragma unroll
      for (int r = 0; r < 16; ++r) {
        int il = (r & 3) + 8 * (r >> 2) + 4 * hi;
        ops[(rowbase + ib * 32 + il) * CC + ch * 128 + cf * 32 + l31] = f2bf(oacc[ib][cf][r]);
      }
}

// ---------------- combine the two K-half partials: obuf = (O0+O1)/(l0+l1) ----------------
__global__ __launch_bounds__(256) void attn_combine(const unsigned short* __restrict__ op0,
                                                    const unsigned short* __restrict__ op1,
                                                    const float* __restrict__ lp,
                                                    unsigned short* __restrict__ obuf) {
  int gid = blockIdx.x * 256 + threadIdx.x;   // 524288 threads, 8 elems each
  int e = gid * 8;
  int b = e >> 20;
  int inner = e & 1048575;
  int n = inner >> 8;
  float linv = 1.f / (lp[b * 8192 + n] + lp[b * 8192 + 4096 + n]);
  size_t off = (size_t)b * 1048576 + inner;
  uint4 u0 = *(const uint4*)(op0 + off);
  uint4 u1 = *(const uint4*)(op1 + off);
  const unsigned short* a = (const unsigned short*)&u0;
  const unsigned short* c = (const unsigned short*)&u1;
  union { unsigned short us[8]; uint4 q; } o;
#pragma unroll
  for (int j = 0; j < 8; ++j)
    o.us[j] = f2bf((bf2f(a[j]) + bf2f(c[j])) * linv);
  *(uint4*)(obuf + e) = o.q;
}

extern "C" void kernel_launch(void* const* d_in, const int* in_sizes, int n_in,
                              void* d_out, int out_size, void* d_ws, size_t ws_size,
                              hipStream_t stream) {
  const float* x     = (const float*)d_in[0];
  // d_in[1] = t (unused)
  const float* gamma = (const float*)d_in[2];
  const float* beta  = (const float*)d_in[3];
  const float* wqkv  = (const float*)d_in[4];
  const float* wproj = (const float*)d_in[5];
  float* out = (float*)d_out;

  // Workspace layout (max 42,468,352 B — footprint proven in rounds 1-2-4-5-6):
  //   [0,1024)            mr (dead after gn_apply)
  //   [1024, 394240)      wq_bf 384 KB (dead after v-GEMM) — lpart (128 KB) overlays @1024
  //   [394240, 525312)    wp_bf 128 KB (live until proj GEMM)
  //   [525312, 8913920)   normed 8 MB (dead after v-GEMM) — opart0 overlays
  //   [8913920, 25691136) qkbuf 16 MB (dead after attn)   — obuf overlays
  //   [25691136,34079744) vbuf 8 MB
  //   [34079744,42468352) opart1 8 MB
  char* p = (char*)d_ws;
  float* mr               = (float*)(p + 0);
  unsigned short* wq_bf   = (unsigned short*)(p + 1024);
  unsigned short* wp_bf   = (unsigned short*)(p + 394240);
  unsigned short* normed  = (unsigned short*)(p + 525312);
  unsigned short* qkbuf   = (unsigned short*)(p + 8913920);
  unsigned short* vbuf    = (unsigned short*)(p + 25691136);
  unsigned short* opart1  = (unsigned short*)(p + 34079744);
  unsigned short* opart0  = normed;                            // overlay (normed dead after v-GEMM)
  float* lpart            = (float*)(p + 1024);                // overlay (wq_bf dead after v-GEMM)
  unsigned short* obuf    = qkbuf;                             // overlay (qkbuf dead after attn)
  unsigned short* wv_bf   = wq_bf + 512 * 256;

  wconv<<<1024, 256, 0, stream>>>(wqkv, wproj, wq_bf, wp_bf);
  gn_stats<<<128, 256, 0, stream>>>(x, mr);
  gn_apply<<<1024, 256, 0, stream>>>(x, mr, gamma, beta, normed);
  // qk[b][n][o] = normed[b][n][:] . wqkv[o][:]  (o<512)
  gemm_bt<0><<<dim3(128, 4), 256, 0, stream>>>(normed, wq_bf, qkbuf, nullptr,
                                               32, 512, (long)NN * CC, 0L, (long)NN * 512, 0L);
  // v[b][c][n] = wv[c][:] . normed[b][n][:]
  gemm_bt<0><<<dim3(64, 4), 256, 0, stream>>>(wv_bf, normed, vbuf, nullptr,
                                              2, 4096, 0L, (long)NN * CC, (long)CC * NN, 0L);
  attn<<<256, 256, 0, stream>>>(qkbuf, vbuf, opart0, opart1, lpart);
  attn_combine<<<2048, 256, 0, stream>>>(opart0, opart1, lpart, obuf);
  // out[b][co][n] = wproj[co][:] . obuf[b][n][:] + x[b][co][n]
  gemm_bt<1><<<dim3(64, 4), 256, 0, stream>>>(wp_bf, obuf, out, x,
                                              2, 4096, 0L, (long)NN * CC, (long)CC * NN, (long)CC * NN);
}

// Round 8
// 194.788 us; speedup vs baseline: 1.1776x; 1.1776x over previous
//
#include <hip/hip_runtime.h>

typedef __bf16 bf16x8 __attribute__((ext_vector_type(8)));
typedef float floatx4 __attribute__((ext_vector_type(4)));
typedef float floatx16 __attribute__((ext_vector_type(16)));
typedef unsigned int u32;

#define BB 4
#define CC 256
#define NN 4096

__device__ __forceinline__ unsigned short f2bf(float f) {
  union { float f; unsigned u; } v; v.f = f;
  unsigned r = v.u + 0x7fffu + ((v.u >> 16) & 1u);
  return (unsigned short)(r >> 16);
}

__device__ __forceinline__ float bf2f(unsigned short s) {
  union { unsigned u; float f; } v; v.u = ((u32)s) << 16;
  return v.f;
}

__device__ __forceinline__ void async16(const void* g, void* l) {
  __builtin_amdgcn_global_load_lds((const __attribute__((address_space(1))) u32*)g,
                                   (__attribute__((address_space(3))) u32*)l, 16, 0, 0);
}

__device__ __forceinline__ u32 fbits(float f) {
  union { float f; u32 u; } v; v.f = f; return v.u;
}

// ---------------- GroupNorm stats: 128 blocks, each reduces a contiguous 32768-float group ----
__global__ __launch_bounds__(256) void gn_stats(const float* __restrict__ x, float* __restrict__ mr) {
  int bg = blockIdx.x;
  const float* p = x + (size_t)bg * 32768;
  int t = threadIdx.x;
  float s = 0.f, q = 0.f;
#pragma unroll
  for (int it = 0; it < 32; ++it) {
    float4 v = *(const float4*)(p + it * 1024 + t * 4);
    s += v.x + v.y + v.z + v.w;
    q += v.x * v.x + v.y * v.y + v.z * v.z + v.w * v.w;
  }
#pragma unroll
  for (int off = 1; off < 64; off <<= 1) {
    s += __shfl_xor(s, off, 64);
    q += __shfl_xor(q, off, 64);
  }
  __shared__ float red[8];
  int w = t >> 6;
  if ((t & 63) == 0) { red[w] = s; red[4 + w] = q; }
  __syncthreads();
  if (t == 0) {
    float S = red[0] + red[1] + red[2] + red[3];
    float Q = red[4] + red[5] + red[6] + red[7];
    float mean = S * (1.f / 32768.f);
    float var = Q * (1.f / 32768.f) - mean * mean;
    mr[bg] = mean;
    mr[128 + bg] = rsqrtf(var + 1e-5f);
  }
}

// ---------------- normalize + transpose to normed[b][n][c] bf16 ----------------
__global__ __launch_bounds__(256) void gn_apply(const float* __restrict__ x, const float* __restrict__ mr,
                                                const float* __restrict__ gamma, const float* __restrict__ beta,
                                                unsigned short* __restrict__ normed) {
  int bid = blockIdx.x;              // b * 4(ctile) * 64(ntile)
  int nt = bid & 63;
  int ct = (bid >> 6) & 3;
  int b = bid >> 8;
  int c0 = ct * 64, n0 = nt * 64;
  __shared__ unsigned short T[64][80];   // [n][c], padded
  int t = threadIdx.x;
#pragma unroll
  for (int it = 0; it < 4; ++it) {
    int idx = it * 256 + t;
    int cl = idx >> 4;
    int n4 = (idx & 15) * 4;
    int c = c0 + cl;
    int bg = b * 32 + (c >> 3);
    float mean = mr[bg], rstd = mr[128 + bg];
    float sc = rstd * gamma[c];
    float sh = beta[c] - mean * sc;
    float4 v = *(const float4*)(x + ((size_t)(b * CC + c)) * NN + n0 + n4);
    T[n4 + 0][cl] = f2bf(v.x * sc + sh);
    T[n4 + 1][cl] = f2bf(v.y * sc + sh);
    T[n4 + 2][cl] = f2bf(v.z * sc + sh);
    T[n4 + 3][cl] = f2bf(v.w * sc + sh);
  }
  __syncthreads();
#pragma unroll
  for (int it = 0; it < 2; ++it) {
    int idx = it * 256 + t;
    int nl = idx >> 3, ck = idx & 7;
    uint4 val;
    unsigned short* pv = (unsigned short*)&val;
#pragma unroll
    for (int j = 0; j < 8; ++j) pv[j] = T[nl][ck * 8 + j];
    *(uint4*)(normed + ((size_t)b * NN + n0 + nl) * CC + c0 + ck * 8) = val;
  }
}

// ---------------- weight fp32 -> bf16 (q rows pre-scaled by log2(e)/sqrt(C)) ----------------
__global__ __launch_bounds__(256) void wconv(const float* __restrict__ wqkv, const float* __restrict__ wproj,
                                             unsigned short* __restrict__ wq_bf, unsigned short* __restrict__ wp_bf) {
  int i = blockIdx.x * 256 + threadIdx.x;      // 1024 blocks -> 262144
  if (i < 196608) {
    float v = wqkv[i];
    if (i < 65536) v *= 0.090168440055560213f;  // log2(e)/16
    wq_bf[i] = f2bf(v);
  } else {
    int j = i - 196608;
    wp_bf[j] = f2bf(wproj[j]);
  }
}

// ---------------- B^T GEMM: C[M][Nc] = A[M][256] * B[Nc][256]^T  (128x128 tiles) ----------------
template <int RESID>
__global__ __launch_bounds__(256) void gemm_bt(const unsigned short* __restrict__ A,
                                               const unsigned short* __restrict__ Bm,
                                               void* __restrict__ Cout, const float* __restrict__ resid,
                                               int mtiles, int ldc,
                                               long sA, long sB, long sC, long sR) {
  int mt = blockIdx.x % mtiles;
  int nt = blockIdx.x / mtiles;
  int b = blockIdx.y;
  int m0 = mt * 128, n0 = nt * 128;
  __shared__ unsigned short As[128][72];
  __shared__ unsigned short Bs[128][72];
  int t = threadIdx.x;
  int w = t >> 6, lane = t & 63;
  int l16 = lane & 15, quad = lane >> 4;
  int wr = w >> 1, wc = w & 1;
  const unsigned short* Ab = A + (size_t)b * sA + (size_t)m0 * 256;
  const unsigned short* Bb = Bm + (size_t)b * sB + (size_t)n0 * 256;
  floatx4 acc[4][4];
#pragma unroll
  for (int m = 0; m < 4; ++m)
#pragma unroll
    for (int n = 0; n < 4; ++n)
#pragma unroll
      for (int r = 0; r < 4; ++r) acc[m][n][r] = 0.f;

  for (int kb = 0; kb < 4; ++kb) {
    __syncthreads();
#pragma unroll
    for (int i = 0; i < 4; ++i) {
      int idx = i * 256 + t;
      int r = idx >> 3, ck = idx & 7;
      *(uint4*)&As[r][ck * 8] = *(const uint4*)(Ab + (size_t)r * 256 + kb * 64 + ck * 8);
      *(uint4*)&Bs[r][ck * 8] = *(const uint4*)(Bb + (size_t)r * 256 + kb * 64 + ck * 8);
    }
    __syncthreads();
#pragma unroll
    for (int kk = 0; kk < 2; ++kk) {
      bf16x8 af[4], bfr[4];
#pragma unroll
      for (int m = 0; m < 4; ++m) af[m] = *(const bf16x8*)&As[wr * 64 + m * 16 + l16][kk * 32 + quad * 8];
#pragma unroll
      for (int n = 0; n < 4; ++n) bfr[n] = *(const bf16x8*)&Bs[wc * 64 + n * 16 + l16][kk * 32 + quad * 8];
#pragma unroll
      for (int m = 0; m < 4; ++m)
#pragma unroll
        for (int n = 0; n < 4; ++n)
          acc[m][n] = __builtin_amdgcn_mfma_f32_16x16x32_bf16(af[m], bfr[n], acc[m][n], 0, 0, 0);
    }
  }
  size_t cb = (size_t)b * sC;
  size_t rb = (size_t)b * sR;
#pragma unroll
  for (int m = 0; m < 4; ++m)
#pragma unroll
    for (int n = 0; n < 4; ++n)
#pragma unroll
      for (int r = 0; r < 4; ++r) {
        int row = m0 + wr * 64 + m * 16 + quad * 4 + r;
        int col = n0 + wc * 64 + n * 16 + l16;
        size_t idx = (size_t)row * ldc + col;
        if (RESID)
          ((float*)Cout)[cb + idx] = acc[m][n][r] + resid[rb + idx];
        else
          ((unsigned short*)Cout)[cb + idx] = f2bf(acc[m][n][r]);
      }
}

// ---------------- fused attention v8: waves = (i-quarter x j-half), full c; zero duplication --
// grid 256 = 1 block/CU, 512 thr, 8 waves = 2/SIMD. Block = (b, qt, kh): Q rows [qt*128,+128),
// K/V rows [kh*2048,+2048). Wave (iq 0..3, jh 0..1) owns O_partial[iq*32..+32][all 256 c] over
// its j-half. Per CU-iter: 256 MFMA (no duplication, v6 had 384) and 256 LDS b128 reads
// (v6: 384). Regs/wave: qreg 64 VGPR + oacc 128 AGPR + temps (~130 arch) < 256 cap.
// DMA double-buffer + swizzled unpadded layouts identical to v6 (verified). Epilogue combines
// the jh pairs' O through LDS (dead K/V buffers), then l via a second small LDS pass.
__global__ __launch_bounds__(512, 2) void attn(const unsigned short* __restrict__ qk,   // [B][N][512] (q|k)
                                               const unsigned short* __restrict__ vbuf, // [B][C][N]
                                               unsigned short* __restrict__ opart0,     // [B][N][C] bf16 (kh=0)
                                               unsigned short* __restrict__ opart1,     // [B][N][C] bf16 (kh=1)
                                               float* __restrict__ lpart) {             // [B*2][N]
  __shared__ __attribute__((aligned(16))) char smem[131072]; // K0|K1|V0|V1, 32 KB each

  int xcd = blockIdx.x & 7, slot = blockIdx.x >> 3;
  int b = xcd >> 1;
  int kh = xcd & 1;
  int i0 = slot * 128;
  int k0 = kh * 32;

  int t = threadIdx.x, w = t >> 6, l = t & 63;
  int l31 = l & 31, hi = l >> 5;
  int jh = w & 1;            // j-half
  int iq = w >> 1;           // i-quarter

  const size_t bqk = (size_t)b * NN * 512;
  const size_t bv = (size_t)b * CC * NN;

  // DMA stage (v6-verified): K [64 j][256 c] 16B-chunk XOR swizzle p^(r&31);
  // V [256 c][64 j] chunk swizzle p^(c&7). Both DMA-compatible (wave-uniform base + lane*16).
  auto stage = [&](int tile, int buf) {
    const unsigned short* kg = qk + bqk + (size_t)tile * 64 * 512 + 256;
    char* kb = smem + buf * 32768;
#pragma unroll
    for (int it = 0; it < 4; ++it) {
      int pp = w * 4 + it;                    // instr-block 0..31 (2 rows each)
      int r = 2 * pp + (l >> 5);
      int c = (l & 31) ^ (r & 31);
      async16(kg + (size_t)r * 512 + c * 8, kb + pp * 1024);
    }
    const unsigned short* vg = vbuf + bv + (size_t)tile * 64;
    char* vb = smem + 65536 + buf * 32768;
    int cj = (l & 7) ^ ((l >> 3) & 7);
#pragma unroll
    for (int it = 0; it < 4; ++it) {
      int pp = w * 4 + it;                    // instr-block 0..31 (8 c-rows each)
      int rc = 8 * pp + (l >> 3);
      async16(vg + (size_t)rc * NN + cj * 8, vb + pp * 1024);
    }
  };

  stage(k0, 0);

  // Q fragments (B-operand): lane = i = i0 + iq*32 + l31, elems c = ks*16 + hi*8 + 0..7
  bf16x8 qreg[16];
  {
    const unsigned short* qp = qk + bqk + (size_t)(i0 + iq * 32 + l31) * 512 + hi * 8;
#pragma unroll
    for (int ks = 0; ks < 16; ++ks)
      qreg[ks] = *(const bf16x8*)(qp + ks * 16);
  }

  floatx16 oacc[8];
#pragma unroll
  for (int cf = 0; cf < 8; ++cf)
#pragma unroll
    for (int r = 0; r < 16; ++r) oacc[cf][r] = 0.f;
  float lacc = 0.f;

  for (int kt = 0; kt < 32; ++kt) {
    int cur = kt & 1;
    __syncthreads();                      // tile kt DMA drained; all waves past prev buf reads
    if (kt < 31) stage(k0 + kt + 1, cur ^ 1);   // in flight during compute below

    const unsigned short* Kc = (const unsigned short*)(smem + cur * 32768);
    const unsigned short* Vc = (const unsigned short*)(smem + 65536 + cur * 32768);

    // S^T = K . Q^T for own j-half (D[m=j][n=i]; lane = i)
    floatx16 st;
#pragma unroll
    for (int r = 0; r < 16; ++r) st[r] = 0.f;
#pragma unroll
    for (int ks = 0; ks < 16; ++ks) {
      bf16x8 kf = *(const bf16x8*)&Kc[(jh * 32 + l31) * 256 + (((ks << 1) | hi) ^ l31) * 8];
      st = __builtin_amdgcn_mfma_f32_32x32x16_bf16(kf, qreg[ks], st, 0, 0, 0);
    }

    // P = exp2(S^T); pack bf16 pairs along j
    u32 pr[8];
#pragma unroll
    for (int k2 = 0; k2 < 8; ++k2) {
      float p0 = __builtin_amdgcn_exp2f(st[2 * k2]);
      float p1 = __builtin_amdgcn_exp2f(st[2 * k2 + 1]);
      lacc += p0 + p1;
      pr[k2] = __builtin_amdgcn_perm(fbits(p1), fbits(p0), 0x07060302u);
    }

    // rearrange into PV A-fragments (elems j = jh*32 + s*16 + hi*8 + 0..7) via hi-half exchange
    union U { u32 u[4]; bf16x8 v; } a0, a1;
    {
      u32 sA = hi ? pr[0] : pr[2], sB = hi ? pr[1] : pr[3];
      u32 rA = (u32)__shfl_xor((int)sA, 32, 64);
      u32 rB = (u32)__shfl_xor((int)sB, 32, 64);
      a0.u[0] = hi ? rA : pr[0]; a0.u[1] = hi ? rB : pr[1];
      a0.u[2] = hi ? pr[2] : rA; a0.u[3] = hi ? pr[3] : rB;
      sA = hi ? pr[4] : pr[6]; sB = hi ? pr[5] : pr[7];
      rA = (u32)__shfl_xor((int)sA, 32, 64);
      rB = (u32)__shfl_xor((int)sB, 32, 64);
      a1.u[0] = hi ? rA : pr[4]; a1.u[1] = hi ? rB : pr[5];
      a1.u[2] = hi ? pr[6] : rA; a1.u[3] = hi ? pr[7] : rB;
    }

    // O_partial += P . V over own j-half; full 256 c (B-frag: lane = c = cf*32+l31, elems = j)
#pragma unroll
    for (int cf = 0; cf < 8; ++cf) {
      const unsigned short* vrow = Vc + (cf * 32 + l31) * 64;
      bf16x8 v0 = *(const bf16x8*)(vrow + (((jh * 4) | hi) ^ (l31 & 7)) * 8);
      oacc[cf] = __builtin_amdgcn_mfma_f32_32x32x16_bf16(a0.v, v0, oacc[cf], 0, 0, 0);
      bf16x8 v1 = *(const bf16x8*)(vrow + (((jh * 4 + 2) | hi) ^ (l31 & 7)) * 8);
      oacc[cf] = __builtin_amdgcn_mfma_f32_32x32x16_bf16(a1.v, v1, oacc[cf], 0, 0, 0);
    }
  }

  // ---- epilogue: combine jh pairs. Phase A: O via 128-KB LDS overlay (dead K/V buffers).
  float l2 = lacc + __shfl_xor(lacc, 32, 64);   // per-lane i = iq*32+l31, own j-half complete

  float* Of = (float*)smem + iq * 8192;         // [32 i][256 c] fp32 per iq (32 KB each)
  __syncthreads();
  if (jh == 1) {
#pragma unroll
    for (int cf = 0; cf < 8; ++cf)
#pragma unroll
      for (int r = 0; r < 16; ++r) {
        int il = (r & 3) + 8 * (r >> 2) + 4 * hi;
        Of[il * 256 + cf * 32 + l31] = oacc[cf][r];
      }
  }
  __syncthreads();
  unsigned short* ops = kh ? opart1 : opart0;
  size_t rowbase = (size_t)b * NN + i0 + iq * 32;
  if (jh == 0) {
#pragma unroll
    for (int cf = 0; cf < 8; ++cf)
#pragma unroll
      for (int r = 0; r < 16; ++r) {
        int il = (r & 3) + 8 * (r >> 2) + 4 * hi;
        float v = oacc[cf][r] + Of[il * 256 + cf * 32 + l31];
        ops[(rowbase + il) * CC + cf * 32 + l31] = f2bf(v);
      }
  }
  __syncthreads();
  // Phase B: l via small LDS pass
  float* Lred = (float*)smem;                   // [8 waves][32]
  if (hi == 0) Lred[w * 32 + l31] = l2;
  __syncthreads();
  if (jh == 0 && hi == 0) {
    size_t pbl = (size_t)(b * 2 + kh) * NN + i0;
    lpart[pbl + iq * 32 + l31] = Lred[(iq * 2) * 32 + l31] + Lred[(iq * 2 + 1) * 32 + l31];
  }
}

// ---------------- proj GEMM with fused K-half combine + residual ----------------
// out[b][co][n] = sum_c wp[co][c] * ((op0[b][n][c]+op1[b][n][c]) / (l0[b][n]+l1[b][n])) + x[b][co][n]
__global__ __launch_bounds__(256) void gemm_proj(const unsigned short* __restrict__ wp,
                                                 const unsigned short* __restrict__ op0,
                                                 const unsigned short* __restrict__ op1,
                                                 const float* __restrict__ lp,
                                                 float* __restrict__ out, const float* __restrict__ x) {
  int mt = blockIdx.x & 1;        // 2 m-tiles over co
  int nt = blockIdx.x >> 1;       // 32 n-tiles
  int b = blockIdx.y;
  int m0 = mt * 128, n0 = nt * 128;
  __shared__ unsigned short As[128][72];
  __shared__ unsigned short Bs[128][72];
  __shared__ float Linv[128];
  int t = threadIdx.x;
  int w = t >> 6, lane = t & 63;
  int l16 = lane & 15, quad = lane >> 4;
  int wr = w >> 1, wc = w & 1;
  const unsigned short* Ab = wp + (size_t)m0 * 256;
  const unsigned short* o0 = op0 + ((size_t)b * NN + n0) * 256;
  const unsigned short* o1 = op1 + ((size_t)b * NN + n0) * 256;
  if (t < 128) Linv[t] = 1.f / (lp[b * 8192 + n0 + t] + lp[b * 8192 + 4096 + n0 + t]);
  floatx4 acc[4][4];
#pragma unroll
  for (int m = 0; m < 4; ++m)
#pragma unroll
    for (int n = 0; n < 4; ++n)
#pragma unroll
      for (int r = 0; r < 4; ++r) acc[m][n][r] = 0.f;

  for (int kb = 0; kb < 4; ++kb) {
    __syncthreads();
#pragma unroll
    for (int i = 0; i < 4; ++i) {
      int idx = i * 256 + t;
      int r = idx >> 3, ck = idx & 7;
      *(uint4*)&As[r][ck * 8] = *(const uint4*)(Ab + (size_t)r * 256 + kb * 64 + ck * 8);
      uint4 u0 = *(const uint4*)(o0 + (size_t)r * 256 + kb * 64 + ck * 8);
      uint4 u1 = *(const uint4*)(o1 + (size_t)r * 256 + kb * 64 + ck * 8);
      float li = Linv[r];
      const unsigned short* pa = (const unsigned short*)&u0;
      const unsigned short* pb = (const unsigned short*)&u1;
      union { unsigned short us[8]; uint4 q; } ob;
#pragma unroll
      for (int j = 0; j < 8; ++j)
        ob.us[j] = f2bf((bf2f(pa[j]) + bf2f(pb[j])) * li);
      *(uint4*)&Bs[r][ck * 8] = ob.q;
    }
    __syncthreads();
#pragma unroll
    for (int kk = 0; kk < 2; ++kk) {
      bf16x8 af[4], bfr[4];
#pragma unroll
      for (int m = 0; m < 4; ++m) af[m] = *(const bf16x8*)&As[wr * 64 + m * 16 + l16][kk * 32 + quad * 8];
#pragma unroll
      for (int n = 0; n < 4; ++n) bfr[n] = *(const bf16x8*)&Bs[wc * 64 + n * 16 + l16][kk * 32 + quad * 8];
#pragma unroll
      for (int m = 0; m < 4; ++m)
#pragma unroll
        for (int n = 0; n < 4; ++n)
          acc[m][n] = __builtin_amdgcn_mfma_f32_16x16x32_bf16(af[m], bfr[n], acc[m][n], 0, 0, 0);
    }
  }
  size_t cb = (size_t)b * CC * NN;
#pragma unroll
  for (int m = 0; m < 4; ++m)
#pragma unroll
    for (int n = 0; n < 4; ++n)
#pragma unroll
      for (int r = 0; r < 4; ++r) {
        int row = m0 + wr * 64 + m * 16 + quad * 4 + r;
        int col = n0 + wc * 64 + n * 16 + l16;
        size_t idx = cb + (size_t)row * NN + col;
        out[idx] = acc[m][n][r] + x[idx];
      }
}

extern "C" void kernel_launch(void* const* d_in, const int* in_sizes, int n_in,
                              void* d_out, int out_size, void* d_ws, size_t ws_size,
                              hipStream_t stream) {
  const float* x     = (const float*)d_in[0];
  // d_in[1] = t (unused)
  const float* gamma = (const float*)d_in[2];
  const float* beta  = (const float*)d_in[3];
  const float* wqkv  = (const float*)d_in[4];
  const float* wproj = (const float*)d_in[5];
  float* out = (float*)d_out;

  // Workspace layout (max 42,468,352 B — proven footprint):
  //   [0,1024)            mr (dead after gn_apply)
  //   [1024, 394240)      wq_bf 384 KB (dead after v-GEMM) — lpart (128 KB) overlays @1024
  //   [394240, 525312)    wp_bf 128 KB (live until proj GEMM)
  //   [525312, 8913920)   normed 8 MB (dead after v-GEMM) — opart0 overlays
  //   [8913920, 25691136) qkbuf 16 MB (dead after attn)
  //   [25691136,34079744) vbuf 8 MB
  //   [34079744,42468352) opart1 8 MB
  char* p = (char*)d_ws;
  float* mr               = (float*)(p + 0);
  unsigned short* wq_bf   = (unsigned short*)(p + 1024);
  unsigned short* wp_bf   = (unsigned short*)(p + 394240);
  unsigned short* normed  = (unsigned short*)(p + 525312);
  unsigned short* qkbuf   = (unsigned short*)(p + 8913920);
  unsigned short* vbuf    = (unsigned short*)(p + 25691136);
  unsigned short* opart1  = (unsigned short*)(p + 34079744);
  unsigned short* opart0  = normed;                            // overlay (normed dead after v-GEMM)
  float* lpart            = (float*)(p + 1024);                // overlay (wq_bf dead after v-GEMM)
  unsigned short* wv_bf   = wq_bf + 512 * 256;

  wconv<<<1024, 256, 0, stream>>>(wqkv, wproj, wq_bf, wp_bf);
  gn_stats<<<128, 256, 0, stream>>>(x, mr);
  gn_apply<<<1024, 256, 0, stream>>>(x, mr, gamma, beta, normed);
  // qk[b][n][o] = normed[b][n][:] . wqkv[o][:]  (o<512)
  gemm_bt<0><<<dim3(128, 4), 256, 0, stream>>>(normed, wq_bf, qkbuf, nullptr,
                                               32, 512, (long)NN * CC, 0L, (long)NN * 512, 0L);
  // v[b][c][n] = wv[c][:] . normed[b][n][:]
  gemm_bt<0><<<dim3(64, 4), 256, 0, stream>>>(wv_bf, normed, vbuf, nullptr,
                                              2, 4096, 0L, (long)NN * CC, (long)CC * NN, 0L);
  attn<<<256, 512, 0, stream>>>(qkbuf, vbuf, opart0, opart1, lpart);
  // out = wproj . combine(op0,op1,l) + x   (combine fused into B-staging)
  gemm_proj<<<dim3(64, 4), 256, 0, stream>>>(wp_bf, opart0, opart1, lpart, out, x);
}